// Round 11
// baseline (107.419 us; speedup 1.0000x reference)
//
#include <hip/hip_runtime.h>
#include <hip/hip_bf16.h>

// Modulated conv2d (StyleGAN2) on MI355X.
// out[b,o] = rsig[b,o] * conv(s[b,:]*x[b,:], W*SCALE)   (shared weights)
// rsig[b,o] = 1/sqrt(sum_i s[b,i]^2 * wsq[o,i] + 1e-8)
// Conv as implicit GEMM: D[o][p] = sum_k Wb[o][k] * Xcl[p][k].
//
// R11: faithful m201 8-phase port. 256x256 tile, 512 thr / 8 waves (4Mx2N),
// per-wave 64x128 (acc 4x8), z-split K (grid 64x2x2 = 256 blk = 1/CU,
// 2 waves/SIMD). LDS 128KB = 2 buf x (A[256][64] 32K + B[256][64] 32K).
// Per K64-tile 4 phases: {reads | stage -> BAR -> lgkm0+schedbar ->
// setprio(1) 16 MFMA setprio(0) -> BAR}. Counted vmcnt(6)@ph4, vmcnt(8)@ph8
// (from the 16-loads/iter issue pattern), never 0 in steady state.
// Region audit: each LDS half's last read phase strictly precedes its
// re-stage phase (A0:ph2->st ph3; B0:ph3->st ph4,5; A1:ph6->st ph7,8;
// B1:ph7->st ph8). Tail = R10's bf16 partials + merge2.

typedef __attribute__((ext_vector_type(4))) float f32x4;
typedef __attribute__((ext_vector_type(8))) short bf16x8;

#define NB    16
#define CIN   512
#define COUT  512
#define KTOT  4608           // CIN * 9
#define NPIX  (NB * 32 * 32) // 16384

#define WAITV8() asm volatile("s_waitcnt vmcnt(8)" ::: "memory")
#define WAITV6() asm volatile("s_waitcnt vmcnt(6)" ::: "memory")
#define WAITV0() asm volatile("s_waitcnt vmcnt(0)" ::: "memory")
#define LGKM0()  asm volatile("s_waitcnt lgkmcnt(0)" ::: "memory")
#define SB0()    __builtin_amdgcn_sched_barrier(0)
#define FENCE()  asm volatile("" ::: "memory")
#define BAR()    { FENCE(); __builtin_amdgcn_s_barrier(); FENCE(); }

__device__ __forceinline__ void gload_lds16(const void* g, void* l) {
  __builtin_amdgcn_global_load_lds(
      (__attribute__((address_space(1))) void*)(g),
      (__attribute__((address_space(3))) void*)(l), 16, 0, 0);
}

__device__ __forceinline__ float bf16bits_to_f32(short v) {
  return __uint_as_float(((unsigned)(unsigned short)v) << 16);
}

// ---- kernel 1: pack weights as wB3[o][(ci>>6)*9+tap][ci&63] bf16 + wsq ----
__global__ __launch_bounds__(256) void pack_w_kernel(
    const float* __restrict__ w, __hip_bfloat16* __restrict__ wB3,
    float* __restrict__ wsq) {
  const int idx = blockIdx.x * 256 + threadIdx.x;   // = o*512 + ci
  const int o = idx >> 9, ci = idx & 511;
  const float* wp = w + (size_t)idx * 9;
  const float WSCALE = 0.014731391274719739f;       // 1/sqrt(512*9)
  float sum = 0.f;
#pragma unroll
  for (int t = 0; t < 9; ++t) {
    float v = wp[t] * WSCALE;
    sum += v * v;
    wB3[(size_t)o * KTOT + (((ci >> 6) * 9 + t) << 6) + (ci & 63)] =
        __float2bfloat16(v);
  }
  wsq[idx] = sum;
}

// ---- kernel 2: rsig[b][o], one wave per (b,o) ----
__global__ __launch_bounds__(256) void calc_rsig_kernel(
    const float* __restrict__ s, const float* __restrict__ wsq,
    float* __restrict__ rsig) {
  const int wid = blockIdx.x * 4 + (threadIdx.x >> 6); // b*512 + o
  const int lane = threadIdx.x & 63;
  const int b = wid >> 9, o = wid & 511;
  const float* sp = s + b * 512;
  const float* wp = wsq + o * 512;
  float sum = 0.f;
#pragma unroll
  for (int i = 0; i < 8; ++i) {
    float sv = sp[lane + i * 64];
    sum += sv * sv * wp[lane + i * 64];
  }
#pragma unroll
  for (int off = 32; off > 0; off >>= 1) sum += __shfl_down(sum, off, 64);
  if (lane == 0) rsig[wid] = 1.0f / sqrtf(sum + 1e-8f);
}

// ---- kernel 3: modulate + NCHW -> padded channels-last bf16 ----
__global__ __launch_bounds__(256) void modulate_kernel(
    const float* __restrict__ x, const float* __restrict__ s,
    __hip_bfloat16* __restrict__ xpad) {
  const int by = blockIdx.x;            // b*32 + y
  const int b = by >> 5, y = by & 31;
  __shared__ __attribute__((aligned(16))) __hip_bfloat16 tile[32][72];
  const int tid = threadIdx.x;
  const int xc = tid & 31;
  const int cr0 = tid >> 5;
  const float* xrow = x + ((size_t)b * 512 * 32 + y) * 32;
  const float* sb = s + b * 512;
  __hip_bfloat16* orow = xpad + (size_t)((b * 34 + y + 1) * 34) * 512;

  for (int ci0 = 0; ci0 < 512; ci0 += 64) {
#pragma unroll
    for (int r = 0; r < 8; ++r) {
      const int cir = r * 8 + cr0;
      const int ci = ci0 + cir;
      float v = xrow[(size_t)ci * 1024 + xc] * sb[ci];
      tile[xc][cir] = __float2bfloat16(v);
    }
    __syncthreads();
    const int xcw = tid >> 3, vec = tid & 7;
    bf16x8 v = *(const bf16x8*)&tile[xcw][vec * 8];
    *(bf16x8*)(orow + (size_t)(xcw + 1) * 512 + ci0 + vec * 8) = v;
    __syncthreads();
  }
}

// ---- kernel 3b: zero only the halo of xpad ----
__global__ __launch_bounds__(256) void halo_zero_kernel(
    __hip_bfloat16* __restrict__ xpad) {
  const int sb = blockIdx.x;           // b*132 + site
  const int b = sb / 132, s = sb - b * 132;
  int y, x;
  if (s < 34)       { y = 0;        x = s; }
  else if (s < 68)  { y = 33;       x = s - 34; }
  else if (s < 100) { y = s - 67;   x = 0; }
  else              { y = s - 99;   x = 33; }
  unsigned* p = (unsigned*)(xpad + (size_t)((b * 34 + y) * 34 + x) * 512);
  p[threadIdx.x] = 0u;   // 256 x 4B = 512 bf16
}

// ---- MFMA quadrant: 2 mi x 4 ni x 2 kk = 16 MFMA ----
#define QUAD(MI0, NI0)                                                        \
  _Pragma("unroll")                                                           \
  for (int mi = (MI0); mi < (MI0) + 2; ++mi)                                  \
    _Pragma("unroll")                                                         \
    for (int ni = (NI0); ni < (NI0) + 4; ++ni)                                \
      _Pragma("unroll")                                                       \
      for (int kk = 0; kk < 2; ++kk)                                          \
        acc[mi][ni] = __builtin_amdgcn_mfma_f32_16x16x32_bf16(                \
            af[mi][kk], bv[ni][kk], acc[mi][ni], 0, 0, 0);

// ---- kernel 4: implicit-GEMM conv, m201 8-phase, 256x256 tile ----
__global__ __launch_bounds__(512, 2) void conv_gemm_kernel(
    const __hip_bfloat16* __restrict__ wB3,   // [512][72][64]
    const __hip_bfloat16* __restrict__ xpad,  // [16][34][34][512]
    const float* __restrict__ rsig,           // [16][512]
    float* __restrict__ out,                  // f32 out (fallback, z=0)
    __hip_bfloat16* __restrict__ p0,          // bf16 partial z=0 (or null)
    __hip_bfloat16* __restrict__ p1) {        // bf16 partial z=1
  extern __shared__ __attribute__((aligned(16))) char ldsc[];

  const int tid = threadIdx.x;
  const int wv = tid >> 6, lane = tid & 63, l15 = lane & 15;
  const int k16 = ((lane >> 4) & 3) << 4;
  const int bo0 = blockIdx.y << 8;        // cout block (256)
  const int bp0 = blockIdx.x << 8;        // pixel block (256; 256 | 1024)
  const int z = blockIdx.z;               // K half (36 K64-tiles each)
  const int bimg = blockIdx.x >> 2;
  const int wr = wv >> 1, wc = wv & 1;    // wave grid 4(M) x 2(N)

  // A staging source (pre-swizzled chunk; rule 21): + h*128*KTOT + ktg*64
  int aoff[2];
#pragma unroll
  for (int rr = 0; rr < 2; ++rr) {
    const int c = rr * 512 + tid, row = c >> 3, sc = (c & 7) ^ (row & 7);
    aoff[rr] = (bo0 + row) * KTOT + sc * 8;
  }
  // B staging source: + xoff(ktg)
  int boff[2][2];
#pragma unroll
  for (int rr = 0; rr < 2; ++rr)
#pragma unroll
    for (int h = 0; h < 2; ++h) {
      const int c = rr * 512 + tid, row = c >> 3, sc = (c & 7) ^ (row & 7);
      const int p = bp0 + h * 128 + row, b = p >> 10, rem = p & 1023,
                y = rem >> 5, xx = rem & 31;
      boff[rr][h] = ((b * 34 + y) * 34 + xx) * 512 + sc * 8;
    }

  auto stA = [&](int par, int ktg, int h) {   // 2 loads/thread = one A half
    char* dst = ldsc + par * 65536 + h * 16384 + tid * 16;
    gload_lds16(wB3 + (size_t)(aoff[0] + h * (128 * KTOT) + (ktg << 6)), dst);
    gload_lds16(wB3 + (size_t)(aoff[1] + h * (128 * KTOT) + (ktg << 6)),
                dst + 8192);
  };
  auto stB = [&](int par, int h, int xo) {    // 2 loads/thread = one B half
    char* dst = ldsc + par * 65536 + 32768 + h * 16384 + tid * 16;
    gload_lds16(xpad + (size_t)(boff[0][h] + xo), dst);
    gload_lds16(xpad + (size_t)(boff[1][h] + xo), dst + 8192);
  };
  auto xoff_of = [&](int ktg) {
    const int g = ktg / 9, tp = ktg - 9 * g;
    return (tp + 31 * (tp / 3)) * 512 + (g << 6);
  };
  auto rdA = [&](const char* buf, int mi, int kk) -> bf16x8 {
    const int row = (wr << 6) + (mi << 4) + l15;
    return *(const bf16x8*)(buf + row * 128 +
                            (((kk << 6) | k16) ^ ((row & 7) << 4)));
  };
  auto rdB = [&](const char* buf, int ni, int kk) -> bf16x8 {
    const int row = (wc << 7) + (ni << 4) + l15;
    return *(const bf16x8*)(buf + row * 128 +
                            (((kk << 6) | k16) ^ ((row & 7) << 4)));
  };

  f32x4 acc[4][8];
#pragma unroll
  for (int mi = 0; mi < 4; ++mi)
#pragma unroll
    for (int ni = 0; ni < 8; ++ni) acc[mi][ni] = f32x4{0.f, 0.f, 0.f, 0.f};

  // Prologue: fully stage tiles 0,1 (16 loads/thread); drain; barrier.
  {
    const int g0 = z * 36;
    const int x0 = xoff_of(g0), x1 = xoff_of(g0 + 1);
    stA(0, g0, 0); stA(0, g0, 1); stB(0, 0, x0); stB(0, 1, x0);
    stA(1, g0 + 1, 0); stA(1, g0 + 1, 1); stB(1, 0, x1); stB(1, 1, x1);
    WAITV0();
    BAR();
  }

  const char* A0 = ldsc;
  const char* B0 = ldsc + 32768;
  const char* A1 = ldsc + 65536;
  const char* B1 = ldsc + 98304;

#pragma unroll 1
  for (int t = 0; t < 18; ++t) {
    const int ktg0 = z * 36 + 2 * t;
    const bool s2 = (2 * t + 2) < 36, s3 = (2 * t + 3) < 36;
    int x2 = 0, x3 = 0;
    if (s2) x2 = xoff_of(ktg0 + 2);
    if (s3) x3 = xoff_of(ktg0 + 3);

    bf16x8 af[4][2], bv[8][2];

    // ================= tile kt0 (buffers A0/B0) =================
    // ph1: read af01 + bv0-3; MFMA Q1 (mi0-1 x ni0-3)
#pragma unroll
    for (int mi = 0; mi < 2; ++mi) {
      af[mi][0] = rdA(A0, mi, 0); af[mi][1] = rdA(A0, mi, 1);
    }
#pragma unroll
    for (int ni = 0; ni < 4; ++ni) {
      bv[ni][0] = rdB(B0, ni, 0); bv[ni][1] = rdB(B0, ni, 1);
    }
    BAR(); LGKM0(); SB0();
    __builtin_amdgcn_s_setprio(1);
    QUAD(0, 0);
    __builtin_amdgcn_s_setprio(0);
    BAR();

    // ph2: read af23; MFMA Q2 (mi2-3 x ni0-3)
#pragma unroll
    for (int mi = 2; mi < 4; ++mi) {
      af[mi][0] = rdA(A0, mi, 0); af[mi][1] = rdA(A0, mi, 1);
    }
    BAR(); LGKM0(); SB0();
    __builtin_amdgcn_s_setprio(1);
    QUAD(2, 0);
    __builtin_amdgcn_s_setprio(0);
    BAR();

    // ph3: read bv4-7; stage A(kt+2) h0 [A0 free after ph2]; Q3 (mi2-3 x ni4-7)
#pragma unroll
    for (int ni = 4; ni < 8; ++ni) {
      bv[ni][0] = rdB(B0, ni, 0); bv[ni][1] = rdB(B0, ni, 1);
    }
    if (s2) stA(0, ktg0 + 2, 0);
    BAR(); LGKM0(); SB0();
    __builtin_amdgcn_s_setprio(1);
    QUAD(2, 4);
    __builtin_amdgcn_s_setprio(0);
    BAR();

    // ph4: stage A(kt+2) h1 + B(kt+2) h0 [B0 free after ph3]; Q4 (mi0-1 x
    // ni4-7); counted vmcnt(6) = ph3+ph4's own 6 loads stay in flight.
    if (s2) { stA(0, ktg0 + 2, 1); stB(0, 0, x2); }
    BAR();
    __builtin_amdgcn_s_setprio(1);
    QUAD(0, 4);
    __builtin_amdgcn_s_setprio(0);
    if (t < 17) { WAITV6(); } else { WAITV0(); }
    BAR();

    // ================= tile kt1 (buffers A1/B1) =================
    // ph5: read af01 + bv0-3 (kt1); stage B(kt+2) h1; Q1
#pragma unroll
    for (int mi = 0; mi < 2; ++mi) {
      af[mi][0] = rdA(A1, mi, 0); af[mi][1] = rdA(A1, mi, 1);
    }
#pragma unroll
    for (int ni = 0; ni < 4; ++ni) {
      bv[ni][0] = rdB(B1, ni, 0); bv[ni][1] = rdB(B1, ni, 1);
    }
    if (s2) stB(0, 1, x2);
    BAR(); LGKM0(); SB0();
    __builtin_amdgcn_s_setprio(1);
    QUAD(0, 0);
    __builtin_amdgcn_s_setprio(0);
    BAR();

    // ph6: read af23 (kt1); Q2
#pragma unroll
    for (int mi = 2; mi < 4; ++mi) {
      af[mi][0] = rdA(A1, mi, 0); af[mi][1] = rdA(A1, mi, 1);
    }
    BAR(); LGKM0(); SB0();
    __builtin_amdgcn_s_setprio(1);
    QUAD(2, 0);
    __builtin_amdgcn_s_setprio(0);
    BAR();

    // ph7: read bv4-7 (kt1); stage A(kt+3) h0 [A1 free after ph6]; Q3
#pragma unroll
    for (int ni = 4; ni < 8; ++ni) {
      bv[ni][0] = rdB(B1, ni, 0); bv[ni][1] = rdB(B1, ni, 1);
    }
    if (s3) stA(1, ktg0 + 3, 0);
    BAR(); LGKM0(); SB0();
    __builtin_amdgcn_s_setprio(1);
    QUAD(2, 4);
    __builtin_amdgcn_s_setprio(0);
    BAR();

    // ph8: stage A(kt+3) h1 + B(kt+3) h0,h1 [B1 free after ph7]; Q4;
    // counted vmcnt(8) = ph7+ph8's own 8 loads stay in flight.
    if (s3) { stA(1, ktg0 + 3, 1); stB(1, 0, x3); stB(1, 1, x3); }
    BAR();
    __builtin_amdgcn_s_setprio(1);
    QUAD(0, 4);
    __builtin_amdgcn_s_setprio(0);
    if (t < 17) { WAITV8(); }
    BAR();
  }

  // Epilogue: scale by rsig; bf16 partial per z (f32 fallback if p0==null).
  // C/D: col(=p)=lane&15, row(=o)=(lane>>4)*4+r
  __hip_bfloat16* pz = z ? p1 : p0;
  const bool f32path = (p0 == nullptr) && (z == 0);
#pragma unroll
  for (int mi = 0; mi < 4; ++mi) {
    const int o = bo0 + (wr << 6) + (mi << 4) + ((lane >> 4) << 2);
    const f32x4 rs = *(const f32x4*)(rsig + (bimg << 9) + o);
#pragma unroll
    for (int ni = 0; ni < 8; ++ni) {
      const int p = bp0 + (wc << 7) + (ni << 4) + l15;
      const int prem = p & 1023;
#pragma unroll
      for (int r = 0; r < 4; ++r) {
        const float v = acc[mi][ni][r] * rs[r];
        const size_t oidx = ((size_t)((bimg << 9) + o + r)) * 1024 + prem;
        if (f32path) out[oidx] = v;
        else pz[oidx] = __float2bfloat16(v);
      }
    }
  }
}

// ---- kernel 5a: merge out = p0 + p1 ----
__global__ __launch_bounds__(256) void merge2_kernel(
    float* __restrict__ out, const __hip_bfloat16* __restrict__ p0,
    const __hip_bfloat16* __restrict__ p1) {
  const size_t i = (size_t)blockIdx.x * 256 + threadIdx.x;
  const bf16x8 a = ((const bf16x8*)p0)[i];
  const bf16x8 b = ((const bf16x8*)p1)[i];
  f32x4 o0, o1;
#pragma unroll
  for (int j = 0; j < 4; ++j) {
    o0[j] = bf16bits_to_f32(a[j]) + bf16bits_to_f32(b[j]);
    o1[j] = bf16bits_to_f32(a[4 + j]) + bf16bits_to_f32(b[4 + j]);
  }
  ((f32x4*)out)[2 * i] = o0;
  ((f32x4*)out)[2 * i + 1] = o1;
}

// ---- kernel 5b: fallback merge out += p1 ----
__global__ __launch_bounds__(256) void merge1_kernel(
    float* __restrict__ out, const __hip_bfloat16* __restrict__ p1) {
  const size_t i = (size_t)blockIdx.x * 256 + threadIdx.x;
  f32x4* o4 = (f32x4*)out + 2 * i;
  f32x4 a = o4[0], b = o4[1];
  const bf16x8 pv = ((const bf16x8*)p1)[i];
#pragma unroll
  for (int j = 0; j < 4; ++j) {
    a[j] += bf16bits_to_f32(pv[j]);
    b[j] += bf16bits_to_f32(pv[4 + j]);
  }
  o4[0] = a;
  o4[1] = b;
}

extern "C" void kernel_launch(void* const* d_in, const int* in_sizes, int n_in,
                              void* d_out, int out_size, void* d_ws,
                              size_t ws_size, hipStream_t stream) {
  const float* x = (const float*)d_in[0];   // [16,512,32,32]
  const float* s = (const float*)d_in[1];   // [16,512]
  const float* w = (const float*)d_in[2];   // [512,512,3,3]
  float* out = (float*)d_out;               // [16,512,32,32] f32

  char* ws = (char*)d_ws;
  const size_t xpad_bytes = (size_t)NB * 34 * 34 * 512 * 2;  // 18,939,904
  const size_t wB_bytes = (size_t)COUT * KTOT * 2;           //  4,718,592
  const size_t wsq_bytes = (size_t)COUT * CIN * 4;           //  1,048,576
  const size_t rsig_bytes = (size_t)NB * COUT * 4;           //     32,768
  const size_t part_bytes = (size_t)NPIX * COUT * 2;         // 16,777,216
  __hip_bfloat16* xpad = (__hip_bfloat16*)ws;
  __hip_bfloat16* wB3 = (__hip_bfloat16*)(ws + xpad_bytes);
  float* wsq = (float*)(ws + xpad_bytes + wB_bytes);
  float* rsig = (float*)(ws + xpad_bytes + wB_bytes + wsq_bytes);
  char* pbase = ws + xpad_bytes + wB_bytes + wsq_bytes + rsig_bytes;
  __hip_bfloat16* p1 = (__hip_bfloat16*)pbase;
  __hip_bfloat16* p0 = (__hip_bfloat16*)(pbase + part_bytes);
  const bool two_partials =
      ws_size >= (xpad_bytes + wB_bytes + wsq_bytes + rsig_bytes +
                  2 * part_bytes);

  const int lds_bytes = 131072;   // 2 x (A 32KB + B 32KB)
  hipFuncSetAttribute((const void*)conv_gemm_kernel,
                      hipFuncAttributeMaxDynamicSharedMemorySize, lds_bytes);

  halo_zero_kernel<<<NB * 132, 256, 0, stream>>>(xpad);
  pack_w_kernel<<<(COUT * CIN) / 256, 256, 0, stream>>>(w, wB3, wsq);
  modulate_kernel<<<NB * 32, 256, 0, stream>>>(x, s, xpad);
  calc_rsig_kernel<<<(NB * COUT) / 4, 256, 0, stream>>>(s, wsq, rsig);
  conv_gemm_kernel<<<dim3(NPIX / 256, COUT / 256, 2), 512, lds_bytes,
                     stream>>>(wB3, xpad, rsig, out,
                               two_partials ? p0 : nullptr, p1);
  const int mblocks = (NPIX * COUT / 8) / 256;   // 4096
  if (two_partials)
    merge2_kernel<<<mblocks, 256, 0, stream>>>(out, p0, p1);
  else
    merge1_kernel<<<mblocks, 256, 0, stream>>>(out, p1);
}